// Round 1
// baseline (156.485 us; speedup 1.0000x reference)
//
#include <hip/hip_runtime.h>
#include <math.h>

// Problem constants (match reference)
#define BB 4096
#define LL 128
#define DD 64
#define PAD 68   // 68 floats/row: 16B-aligned rows, minimal-pass b128 LDS reads

__global__ __launch_bounds__(256, 4) void softmax_attn_cos_kernel(
    const int* __restrict__ ids_a, const int* __restrict__ mask_a,
    const int* __restrict__ ids_b, const int* __restrict__ mask_b,
    const float* __restrict__ mu_table, const float* __restrict__ feat_table,
    float* __restrict__ out)
{
    __shared__ int   s_ids[LL];
    __shared__ float s_m[LL];
    __shared__ float s_mu[LL][PAD];
    __shared__ float s_q[DD];
    __shared__ float s_part[4][DD];
    __shared__ float s_sc[LL];
    __shared__ float s_mean[2][DD];
    __shared__ float s_sum;

    const int tid  = threadIdx.x;
    const int d    = tid & 63;
    const int lsub = tid >> 6;      // 0..3
    const int b    = blockIdx.x;

    for (int side = 0; side < 2; ++side) {
        const int* ids = side ? ids_b  : ids_a;
        const int* msk = side ? mask_b : mask_a;

        // ---- phase 1: load ids + mask ----
        if (tid < LL) {
            s_ids[tid] = ids[b * LL + tid];
            s_m[tid]   = (float)msk[b * LL + tid];
        }
        __syncthreads();

        // ---- phase 2: gather mu rows (coalesced 256B/row) + masked partial sum ----
        float qacc = 0.f;
        #pragma unroll 4
        for (int j = 0; j < 32; ++j) {
            const int l  = lsub * 32 + j;
            const int id = s_ids[l];
            const float v = mu_table[(size_t)id * DD + d];
            s_mu[l][d] = v;
            qacc += v * s_m[l];
        }
        s_part[lsub][d] = qacc;
        __syncthreads();

        // ---- q = masked mean (wave 0) ----
        if (tid < 64) {
            float mv = s_m[tid] + s_m[tid + 64];
            #pragma unroll
            for (int off = 32; off; off >>= 1) mv += __shfl_xor(mv, off, 64);
            const float denom = fmaxf(mv, 1.0f);
            const float q = (s_part[0][d] + s_part[1][d] + s_part[2][d] + s_part[3][d]) / denom;
            s_q[d] = q;
        }
        __syncthreads();

        // ---- phase 3: scores[l] = mu[l] . q  (float4 LDS reads) ----
        if (tid < LL) {
            const float4* row = (const float4*)(&s_mu[tid][0]);
            const float4* qv4 = (const float4*)(&s_q[0]);
            float acc = 0.f;
            #pragma unroll
            for (int k = 0; k < 16; ++k) {
                const float4 v  = row[k];
                const float4 q4 = qv4[k];
                acc += v.x * q4.x + v.y * q4.y + v.z * q4.z + v.w * q4.w;
            }
            s_sc[tid] = (s_m[tid] > 0.5f) ? acc : -1e9f;
        }
        __syncthreads();

        // ---- phase 4: softmax over 128 scores (wave 0 butterfly) ----
        if (tid < 64) {
            const float s1 = s_sc[tid], s2 = s_sc[tid + 64];
            float mx = fmaxf(s1, s2);
            #pragma unroll
            for (int off = 32; off; off >>= 1) mx = fmaxf(mx, __shfl_xor(mx, off, 64));
            const float e1 = expf(s1 - mx), e2 = expf(s2 - mx);
            s_sc[tid] = e1; s_sc[tid + 64] = e2;
            float sm = e1 + e2;
            #pragma unroll
            for (int off = 32; off; off >>= 1) sm += __shfl_xor(sm, off, 64);
            if (tid == 0) s_sum = sm;
        }
        __syncthreads();

        // ---- phase 5: out[d] = sum_l attn[l] * feat[id[l]][d] (coalesced gather) ----
        float oacc = 0.f;
        #pragma unroll 4
        for (int j = 0; j < 32; ++j) {
            const int l = lsub * 32 + j;
            oacc += s_sc[l] * feat_table[(size_t)s_ids[l] * DD + d];
        }
        s_part[lsub][d] = oacc;
        __syncthreads();
        if (tid < 64) {
            const float o = (s_part[0][d] + s_part[1][d] + s_part[2][d] + s_part[3][d]) / s_sum;
            s_mean[side][d] = o;
        }
        __syncthreads();
    }

    // ---- cosine similarity * 5 (wave 0 butterfly) ----
    if (tid < 64) {
        const float a = s_mean[0][tid], c = s_mean[1][tid];
        float dt = a * c, na = a * a, nb = c * c;
        #pragma unroll
        for (int off = 32; off; off >>= 1) {
            dt += __shfl_xor(dt, off, 64);
            na += __shfl_xor(na, off, 64);
            nb += __shfl_xor(nb, off, 64);
        }
        if (tid == 0) {
            const float denom = fmaxf(sqrtf(na), 1e-8f) * fmaxf(sqrtf(nb), 1e-8f);
            out[b] = 5.0f * dt / denom;
        }
    }
}

extern "C" void kernel_launch(void* const* d_in, const int* in_sizes, int n_in,
                              void* d_out, int out_size, void* d_ws, size_t ws_size,
                              hipStream_t stream) {
    const int*   ids_a  = (const int*)d_in[0];
    const int*   mask_a = (const int*)d_in[1];
    const int*   ids_b  = (const int*)d_in[2];
    const int*   mask_b = (const int*)d_in[3];
    const float* mu     = (const float*)d_in[4];
    const float* feat   = (const float*)d_in[5];
    float* out = (float*)d_out;

    softmax_attn_cos_kernel<<<BB, 256, 0, stream>>>(
        ids_a, mask_a, ids_b, mask_b, mu, feat, out);
}